// Round 9
// baseline (377.868 us; speedup 1.0000x reference)
//
#include <hip/hip_runtime.h>
#include <hip/hip_bf16.h>
#include <math.h>

// ---------------------------------------------------------------------------
// PositionalAttentionPooling — MFMA branch GEMMs + unified node-list gather
//   branch2: barrier-free MFMA, writes UNIFIED tEU[N][80], eWnU[N][128]
//            (query rows 0..NQ-1, product rows NQ..NQ+P-1)
//   node list: per-segment packed entries row<<6|pos (product rows repeated)
//   segsum3: gather over node list (no atomics, no cnt weighting, no hist)
//   coarse:  segmean -> @Wc^T + bn -> coarseWc
//   att4:    fused attention+pool, wave/segment, 8-node ILP batches
// ---------------------------------------------------------------------------

constexpr int D   = 128;
constexpr int DL  = 78;
constexpr int MSL = 50;
constexpr int RP  = 80;   // padded row stride for tEU

typedef __attribute__((ext_vector_type(8))) short bfrag8;   // 8 bf16 (4 VGPR)
typedef __attribute__((ext_vector_type(4))) float facc4;    // 4 f32 acc
typedef __attribute__((ext_vector_type(4))) short short4v;  // 8B

__device__ __forceinline__ float sigmoidf_(float x) {
    return 1.f / (1.f + __expf(-x));
}
__device__ __forceinline__ float ftanh(float x) {
    float e = __expf(2.f * x);
    return 1.f - 2.f * __builtin_amdgcn_rcpf(e + 1.f);
}

// ---- swizzled LDS helpers (row stride 256B, XOR bits 4..6 by row&7) -------
__device__ __forceinline__ char* ldsAddr(__hip_bfloat16* base, int row, int byte_in_row) {
    return reinterpret_cast<char*>(base) + row * 256 + (byte_in_row ^ ((row & 7) << 4));
}
__device__ __forceinline__ bfrag8 ldsR16(const __hip_bfloat16* base, int row, int byte_in_row) {
    return *reinterpret_cast<const bfrag8*>(
        reinterpret_cast<const char*>(base) + row * 256 + (byte_in_row ^ ((row & 7) << 4)));
}
__device__ __forceinline__ short4v ldsR8(const __hip_bfloat16* base, int row, int byte_in_row) {
    return *reinterpret_cast<const short4v*>(
        reinterpret_cast<const char*>(base) + row * 256 + (byte_in_row ^ ((row & 7) << 4)));
}

__device__ __forceinline__ bfrag8 cvt8(float4 a, float4 b) {
    __hip_bfloat16 t[8] = {__float2bfloat16(a.x), __float2bfloat16(a.y),
                           __float2bfloat16(a.z), __float2bfloat16(a.w),
                           __float2bfloat16(b.x), __float2bfloat16(b.y),
                           __float2bfloat16(b.z), __float2bfloat16(b.w)};
    return *reinterpret_cast<bfrag8*>(t);
}

// --- tables: tpos = tanh(pos_table); posWn = tpos @ Wn2^T
__global__ __launch_bounds__(256) void k_tables2(
    const float* __restrict__ pos_table, const float* __restrict__ Wn,
    float* __restrict__ tpos, float* __restrict__ posWn) {
    __shared__ float tposL[MSL * MSL];
    int t = threadIdx.x;
    for (int o = t; o < MSL * MSL; o += 256) tposL[o] = tanhf(pos_table[o]);
    __syncthreads();
    if (blockIdx.x == 0)
        for (int o = t; o < MSL * MSL; o += 256) tpos[o] = tposL[o];
    for (int o = blockIdx.x * 256 + t; o < MSL * D; o += gridDim.x * 256) {
        int r = o >> 7, d = o & 127;
        float acc = 0.f;
        #pragma unroll 10
        for (int j = 0; j < MSL; ++j) acc += tposL[r * MSL + j] * Wn[d * D + DL + j];
        posWn[o] = acc;
    }
}

// --- convW: bf16 weight tables
__global__ __launch_bounds__(256) void k_convW(
    const float* __restrict__ Wq, const float* __restrict__ Wp, const float* __restrict__ Wn,
    __hip_bfloat16* __restrict__ Wqbf, __hip_bfloat16* __restrict__ Wpbf,
    __hip_bfloat16* __restrict__ Wnbf) {
    int i = blockIdx.x * 256 + threadIdx.x;
    if (i < 80 * 128) {
        int n = i >> 7;
        Wqbf[i] = __float2bfloat16((n < DL) ? Wq[i] : 0.f);
        Wpbf[i] = __float2bfloat16((n < DL) ? Wp[i] : 0.f);
    } else if (i < 80 * 128 + 128 * 128) {
        int o = i - 80 * 128;
        int j = o & 127;
        Wnbf[o] = __float2bfloat16((j < DL) ? Wn[o] : 0.f);
    }
}

// --- exclusive scan of cnt -> prodOff
__global__ void k_scanA(const int* __restrict__ cnt, int P, int* __restrict__ chunkSum) {
    __shared__ int s[256];
    int p = blockIdx.x * 256 + threadIdx.x;
    s[threadIdx.x] = (p < P) ? cnt[p] : 0;
    __syncthreads();
    for (int st = 128; st > 0; st >>= 1) {
        if (threadIdx.x < st) s[threadIdx.x] += s[threadIdx.x + st];
        __syncthreads();
    }
    if (threadIdx.x == 0) chunkSum[blockIdx.x] = s[0];
}
__global__ __launch_bounds__(1024) void k_scanB(
    const int* __restrict__ chunkSum, int nC, int* __restrict__ chunkOff) {
    __shared__ int s[1024];
    int t = threadIdx.x;
    int carry = 0;
    for (int base = 0; base < nC; base += 1024) {
        int v = (base + t < nC) ? chunkSum[base + t] : 0;
        s[t] = v;
        __syncthreads();
        for (int st = 1; st < 1024; st <<= 1) {
            int add = (t >= st) ? s[t - st] : 0;
            __syncthreads();
            s[t] += add;
            __syncthreads();
        }
        if (base + t < nC) chunkOff[base + t] = carry + s[t] - v;  // exclusive
        carry += s[1023];
        __syncthreads();
    }
}
__global__ void k_scanC(const int* __restrict__ cnt, int P, const int* __restrict__ chunkOff,
                        int* __restrict__ prodOff) {
    __shared__ int s[256];
    int t = threadIdx.x;
    int p = blockIdx.x * 256 + t;
    int v = (p < P) ? cnt[p] : 0;
    s[t] = v;
    __syncthreads();
    for (int st = 1; st < 256; st <<= 1) {
        int add = (t >= st) ? s[t - st] : 0;
        __syncthreads();
        s[t] += add;
        __syncthreads();
    }
    if (p < P) prodOff[p] = chunkOff[blockIdx.x] + s[t] - v;  // exclusive
}

// --- node count per segment (queries 1 each, products cnt each)
__global__ void k_cnt2(const int* __restrict__ qbatch, const int* __restrict__ pbatch,
                       const int* __restrict__ cnt, int NQ, int P, int* __restrict__ nodeCnt) {
    int i = blockIdx.x * 256 + threadIdx.x;
    if (i < NQ) {
        atomicAdd(&nodeCnt[qbatch[i]], 1);
    } else if (i < NQ + P) {
        int p = i - NQ;
        atomicAdd(&nodeCnt[pbatch[p]], cnt[p]);
    }
}
__global__ __launch_bounds__(1024) void k_scanSeg(
    const int* __restrict__ nodeCnt, int B, int* __restrict__ segOff, int* __restrict__ cursor) {
    __shared__ int s[1024];
    int t = threadIdx.x;
    int carry = 0;
    for (int base = 0; base < B; base += 1024) {
        int v = (base + t < B) ? nodeCnt[base + t] : 0;
        s[t] = v;
        __syncthreads();
        for (int st = 1; st < 1024; st <<= 1) {
            int add = (t >= st) ? s[t - st] : 0;
            __syncthreads();
            s[t] += add;
            __syncthreads();
        }
        if (base + t < B) {
            int e = carry + s[t] - v;
            segOff[base + t] = e;
            cursor[base + t] = e;
        }
        carry += s[1023];
        __syncthreads();
    }
    if (t == 0) segOff[B] = carry;
}
// --- node list: packed row<<6|pos ; product rows offset by NQ, repeated cnt×
__global__ void k_rank2(const int* __restrict__ qbatch, const int* __restrict__ pbatch,
                        const int* __restrict__ qpos, const int* __restrict__ ppos,
                        const int* __restrict__ cnt, const int* __restrict__ prodOff,
                        int NQ, int P, int* __restrict__ cursor, int* __restrict__ nodeIdx) {
    int i = blockIdx.x * 256 + threadIdx.x;
    if (i < NQ) {
        int slot = atomicAdd(&cursor[qbatch[i]], 1);
        nodeIdx[slot] = (i << 6) | qpos[i];
    } else if (i < NQ + P) {
        int p = i - NQ;
        int c = cnt[p], off = prodOff[p];
        int slot = atomicAdd(&cursor[pbatch[p]], c);
        for (int j = 0; j < c; ++j)
            nodeIdx[slot + j] = ((NQ + p) << 6) | ppos[off + j];
    }
}

// --- merged MFMA branch kernel: 64 rows/block, 4 waves, ZERO barriers
//     writes UNIFIED tEU (row base 0 / NQ) and eWnU
__global__ __launch_bounds__(256) void k_branch2(
    const float* __restrict__ qfeat, const float* __restrict__ pfeat,
    const __hip_bfloat16* __restrict__ Wqbf, const __hip_bfloat16* __restrict__ Wpbf,
    const float* __restrict__ bq, const float* __restrict__ bp,
    const __hip_bfloat16* __restrict__ Wnbf,
    int NQ, int P, int qBlocks,
    __hip_bfloat16* __restrict__ tEU, __hip_bfloat16* __restrict__ eWnU) {
    const bool isQ = (int)blockIdx.x < qBlocks;
    const int r0 = (isQ ? blockIdx.x : blockIdx.x - qBlocks) * 64;
    const float* feat = isQ ? qfeat : pfeat;
    const __hip_bfloat16* Wbf = isQ ? Wqbf : Wpbf;
    const float* bias = isQ ? bq : bp;
    const int Nrows = isQ ? NQ : P;
    const int rowBase = isQ ? 0 : NQ;

    __shared__ __hip_bfloat16 linL[64 * 128];
    __shared__ __hip_bfloat16 eWnL[64 * 128];
    int t = threadIdx.x;
    int l = t & 63, w = t >> 6;
    int lr = l & 15, lq = l >> 4;
    int am = w * 16 + lr;

    if (l < 16) {
        bfrag8 z = {0, 0, 0, 0, 0, 0, 0, 0};
        *reinterpret_cast<bfrag8*>(ldsAddr(linL, w * 16 + l, 160)) = z;
        *reinterpret_cast<bfrag8*>(ldsAddr(linL, w * 16 + l, 176)) = z;
    }

    int gra = r0 + am;
    const float* frow = &feat[(size_t)(gra < Nrows ? gra : Nrows - 1) * 128];
    bfrag8 a[4];
    #pragma unroll
    for (int kt = 0; kt < 4; ++kt) {
        float4 u = *reinterpret_cast<const float4*>(&frow[kt * 32 + lq * 8]);
        float4 v = *reinterpret_cast<const float4*>(&frow[kt * 32 + lq * 8 + 4]);
        a[kt] = cvt8(u, v);
    }

    facc4 c1[5];
    #pragma unroll
    for (int nt = 0; nt < 5; ++nt) { facc4 z = {0.f, 0.f, 0.f, 0.f}; c1[nt] = z; }
    #pragma unroll
    for (int nt = 0; nt < 5; ++nt) {
        #pragma unroll
        for (int kt = 0; kt < 4; ++kt) {
            bfrag8 b = *reinterpret_cast<const bfrag8*>(&Wbf[(nt * 16 + lr) * 128 + kt * 32 + lq * 8]);
            c1[nt] = __builtin_amdgcn_mfma_f32_16x16x32_bf16(a[kt], b, c1[nt], 0, 0, 0);
        }
    }

    #pragma unroll
    for (int nt = 0; nt < 5; ++nt) {
        int n = nt * 16 + lr;
        float bs = (n < DL) ? bias[n] : 0.f;
        #pragma unroll
        for (int j = 0; j < 4; ++j) {
            int m = w * 16 + lq * 4 + j;
            float tv = (n < DL) ? ftanh(c1[nt][j] + bs) : 0.f;
            *reinterpret_cast<__hip_bfloat16*>(ldsAddr(linL, m, 2 * n)) = __float2bfloat16(tv);
        }
    }

    {
        int r = w * 16 + (l >> 2), c = l & 3;
        int gr = r0 + r;
        #pragma unroll
        for (int j = 0; j < 5; ++j) {
            short4v v = ldsR8(linL, r, c * 40 + j * 8);
            if (gr < Nrows)
                *reinterpret_cast<short4v*>(&tEU[(size_t)(rowBase + gr) * RP + c * 20 + j * 4]) = v;
        }
    }

    bfrag8 a2[3];
    #pragma unroll
    for (int kt = 0; kt < 3; ++kt) a2[kt] = ldsR16(linL, am, kt * 64 + lq * 16);
    facc4 c2[8];
    #pragma unroll
    for (int nt = 0; nt < 8; ++nt) { facc4 z = {0.f, 0.f, 0.f, 0.f}; c2[nt] = z; }
    #pragma unroll
    for (int nt = 0; nt < 8; ++nt) {
        #pragma unroll
        for (int kt = 0; kt < 3; ++kt) {
            bfrag8 b = *reinterpret_cast<const bfrag8*>(&Wnbf[(nt * 16 + lr) * 128 + kt * 32 + lq * 8]);
            c2[nt] = __builtin_amdgcn_mfma_f32_16x16x32_bf16(a2[kt], b, c2[nt], 0, 0, 0);
        }
    }
    #pragma unroll
    for (int nt = 0; nt < 8; ++nt) {
        int d2 = nt * 16 + lr;
        #pragma unroll
        for (int j = 0; j < 4; ++j) {
            int m = w * 16 + lq * 4 + j;
            *reinterpret_cast<__hip_bfloat16*>(ldsAddr(eWnL, m, 2 * d2)) =
                __float2bfloat16(c2[nt][j]);
        }
    }
    {
        int r = w * 16 + (l >> 2), c = l & 3;
        int gr = r0 + r;
        #pragma unroll
        for (int j = 0; j < 4; ++j) {
            bfrag8 v = ldsR16(eWnL, r, c * 64 + j * 16);
            if (gr < Nrows)
                *reinterpret_cast<bfrag8*>(&eWnU[(size_t)(rowBase + gr) * 128 + c * 32 + j * 8]) = v;
        }
    }
}

// --- segsum via node list gather: block(128) per segment
__global__ __launch_bounds__(128) void k_segsum3(
    const __hip_bfloat16* __restrict__ tEU, const int* __restrict__ nodeIdx,
    const int* __restrict__ segOff, const float* __restrict__ tpos, int B,
    float* __restrict__ segsum, float* __restrict__ segcnt) {
    int b = blockIdx.x, t = threadIdx.x;
    int s0 = segOff[b], s1 = segOff[b + 1];
    float acc = 0.f;
    if (t < DL) {
        for (int i = s0; i < s1; i += 4) {
            #pragma unroll
            for (int j = 0; j < 4; ++j) {
                if (i + j < s1) {
                    int row = nodeIdx[i + j] >> 6;
                    acc += __bfloat162float(tEU[(size_t)row * RP + t]);
                }
            }
        }
        segsum[(size_t)b * D + t] = acc;
    } else {
        int k = t - DL;  // 0..49
        for (int i = s0; i < s1; i += 4) {
            #pragma unroll
            for (int j = 0; j < 4; ++j) {
                if (i + j < s1) {
                    int pos = nodeIdx[i + j] & 63;
                    acc += tpos[pos * MSL + k];
                }
            }
        }
        segsum[(size_t)b * D + DL + k] = acc;
        if (k == 0) segcnt[b] = (float)(s1 - s0);
    }
}

// --- coarse = segsum/cnt ; coarseWc = coarse @ Wc^T + bn
__global__ __launch_bounds__(256) void k_coarse(
    const float* __restrict__ segsum, const float* __restrict__ segcnt,
    const float* __restrict__ Wc, const float* __restrict__ bn, int B,
    float* __restrict__ coarseWc) {
    __shared__ __hip_bfloat16 WcL[128 * 130];
    __shared__ float cL[16 * 128];
    int t = threadIdx.x;
    int b0 = blockIdx.x * 16;
    for (int o = t; o < D * D; o += 256) {
        int d = o >> 7, k = o & 127;
        WcL[d * 130 + k] = __float2bfloat16(Wc[o]);
    }
    for (int o = t; o < 16 * D; o += 256) {
        int bb = o >> 7, d = o & 127;
        int b = b0 + bb;
        cL[o] = (b < B) ? segsum[(size_t)b * D + d] / fmaxf(segcnt[b], 1.f) : 0.f;
    }
    __syncthreads();
    for (int o = t; o < 16 * D; o += 256) {
        int bb = o >> 7, d = o & 127;
        int b = b0 + bb;
        if (b >= B) continue;
        float acc = bn[d];
        const float* cr = &cL[bb * 128];
        const __hip_bfloat16* wr = &WcL[d * 130];
        #pragma unroll 8
        for (int j = 0; j < D; ++j) acc += cr[j] * __bfloat162float(wr[j]);
        coarseWc[(size_t)b * D + d] = acc;
    }
}

// --- FUSED attention + weighted segment-sum: wave per segment, 8-node batches
__global__ __launch_bounds__(256) void k_att4(
    const __hip_bfloat16* __restrict__ eWnU, const __hip_bfloat16* __restrict__ tEU,
    const float* __restrict__ coarseWc, const float* __restrict__ posWn,
    const float* __restrict__ tpos, const float* __restrict__ Wa,
    const int* __restrict__ nodeIdx, const int* __restrict__ segOff,
    const float* __restrict__ segcnt, int B, float* __restrict__ out) {
    int wv = threadIdx.x >> 6, l = threadIdx.x & 63;
    int b = blockIdx.x * 4 + wv;
    if (b >= B) return;

    float cw0 = coarseWc[(size_t)b * D + l];
    float cw1 = coarseWc[(size_t)b * D + 64 + l];
    float wa0 = Wa[l], wa1 = Wa[64 + l];
    float acc0 = 0.f, acc1 = 0.f, posacc = 0.f;
    int s0 = segOff[b], s1 = segOff[b + 1];

    for (int i = s0; i < s1; i += 8) {
        float part[8];
        int   row[8], pos[8];
        #pragma unroll
        for (int j = 0; j < 8; ++j) {
            bool on = (i + j) < s1;
            int pk = on ? nodeIdx[i + j] : 0;
            row[j] = pk >> 6;
            pos[j] = pk & 63;
            float z0 = __bfloat162float(eWnU[(size_t)row[j] * D + l])      + cw0 + posWn[pos[j] * D + l];
            float z1 = __bfloat162float(eWnU[(size_t)row[j] * D + 64 + l]) + cw1 + posWn[pos[j] * D + 64 + l];
            part[j] = on ? (sigmoidf_(z0) * wa0 + sigmoidf_(z1) * wa1) : 0.f;
        }
        #pragma unroll
        for (int m = 1; m < 64; m <<= 1) {
            #pragma unroll
            for (int j = 0; j < 8; ++j) part[j] += __shfl_xor(part[j], m, 64);
        }
        #pragma unroll
        for (int j = 0; j < 8; ++j) {
            acc0 += part[j] * __bfloat162float(tEU[(size_t)row[j] * RP + l]);
            if (l < 14) acc1 += part[j] * __bfloat162float(tEU[(size_t)row[j] * RP + 64 + l]);
            else        posacc += part[j] * tpos[pos[j] * MSL + (l - 14)];
        }
    }

    float inv = 1.f / fmaxf(segcnt[b], 1.f);
    out[(size_t)b * D + l] = acc0 * inv;
    out[(size_t)b * D + 64 + l] = (l < 14 ? acc1 : posacc) * inv;
}

extern "C" void kernel_launch(void* const* d_in, const int* in_sizes, int n_in,
                              void* d_out, int out_size, void* d_ws, size_t ws_size,
                              hipStream_t stream) {
    const float* query_feat   = (const float*)d_in[0];
    const float* product_feat = (const float*)d_in[1];
    const float* Wq = (const float*)d_in[2];
    const float* bq = (const float*)d_in[3];
    const float* Wp = (const float*)d_in[4];
    const float* bp = (const float*)d_in[5];
    const float* pos_table = (const float*)d_in[6];
    const float* Wn = (const float*)d_in[7];
    const float* bn = (const float*)d_in[8];
    const float* Wc = (const float*)d_in[9];
    const float* Wa = (const float*)d_in[10];
    const int* qpos   = (const int*)d_in[11];
    const int* ppos   = (const int*)d_in[12];
    const int* qbatch = (const int*)d_in[13];
    const int* pbatch = (const int*)d_in[14];
    const int* cnt    = (const int*)d_in[15];

    int NQ = in_sizes[11];
    int T  = in_sizes[12];   // total product nodes
    int P  = in_sizes[15];
    int B  = out_size / D;
    int NR = NQ + P;         // rows in unified tables
    int NN = NQ + T;         // total node-list entries
    float* out = (float*)d_out;

    // workspace layout (256B aligned chunks)
    char* w = (char*)d_ws;
    size_t off = 0;
    auto take = [&](size_t bytes) -> char* {
        char* p = w + off;
        off = (off + bytes + 255) & ~(size_t)255;
        return p;
    };
    // zero region: nodeCnt only
    int*   nodeCnt = (int*)  take((size_t)B * 4);
    size_t zeroBytes = off;
    float* segsum   = (float*)take((size_t)B * D * 4);
    float* segcnt   = (float*)take((size_t)B * 4);
    float* coarseWc = (float*)take((size_t)B * D * 4);
    float* tpos  = (float*)take(MSL * MSL * 4);
    float* posWn = (float*)take(MSL * D * 4);
    __hip_bfloat16* Wqbf = (__hip_bfloat16*)take(80 * 128 * 2);
    __hip_bfloat16* Wpbf = (__hip_bfloat16*)take(80 * 128 * 2);
    __hip_bfloat16* Wnbf = (__hip_bfloat16*)take(128 * 128 * 2);
    int nC = (P + 255) / 256;
    int* chunkSum = (int*)take((size_t)nC * 4);
    int* chunkOff = (int*)take((size_t)nC * 4);
    int* prodOff  = (int*)take((size_t)P * 4);
    int* segOffA  = (int*)take((size_t)(B + 1) * 4);
    int* cursor   = (int*)take((size_t)B * 4);
    int* nodeIdx  = (int*)take((size_t)NN * 4);
    __hip_bfloat16* tEU  = (__hip_bfloat16*)take((size_t)NR * RP * 2);
    __hip_bfloat16* eWnU = (__hip_bfloat16*)take((size_t)NR * D * 2);
    (void)ws_size; (void)n_in;

    hipMemsetAsync(nodeCnt, 0, zeroBytes, stream);

    hipLaunchKernelGGL(k_tables2, dim3(8), dim3(256), 0, stream, pos_table, Wn, tpos, posWn);
    hipLaunchKernelGGL(k_convW, dim3((80 * 128 + 128 * 128 + 255) / 256), dim3(256), 0, stream,
                       Wq, Wp, Wn, Wqbf, Wpbf, Wnbf);
    hipLaunchKernelGGL(k_scanA, dim3(nC), dim3(256), 0, stream, cnt, P, chunkSum);
    hipLaunchKernelGGL(k_scanB, dim3(1), dim3(1024), 0, stream, chunkSum, nC, chunkOff);
    hipLaunchKernelGGL(k_scanC, dim3(nC), dim3(256), 0, stream, cnt, P, chunkOff, prodOff);

    // unified node list (row<<6|pos), grouped by segment
    hipLaunchKernelGGL(k_cnt2, dim3((NR + 255) / 256), dim3(256), 0, stream,
                       qbatch, pbatch, cnt, NQ, P, nodeCnt);
    hipLaunchKernelGGL(k_scanSeg, dim3(1), dim3(1024), 0, stream, nodeCnt, B, segOffA, cursor);
    hipLaunchKernelGGL(k_rank2, dim3((NR + 255) / 256), dim3(256), 0, stream,
                       qbatch, pbatch, qpos, ppos, cnt, prodOff, NQ, P, cursor, nodeIdx);

    int qBlocks = (NQ + 63) / 64, pBlocksBr = (P + 63) / 64;
    hipLaunchKernelGGL(k_branch2, dim3(qBlocks + pBlocksBr), dim3(256), 0, stream,
                       query_feat, product_feat, Wqbf, Wpbf, bq, bp, Wnbf,
                       NQ, P, qBlocks, tEU, eWnU);

    hipLaunchKernelGGL(k_segsum3, dim3(B), dim3(128), 0, stream,
                       tEU, nodeIdx, segOffA, tpos, B, segsum, segcnt);
    hipLaunchKernelGGL(k_coarse, dim3((B + 15) / 16), dim3(256), 0, stream,
                       segsum, segcnt, Wc, bn, B, coarseWc);

    hipLaunchKernelGGL(k_att4, dim3((B + 3) / 4), dim3(256), 0, stream,
                       eWnU, tEU, coarseWc, posWn, tpos, Wa,
                       nodeIdx, segOffA, segcnt, B, out);
}

// Round 10
// 322.756 us; speedup vs baseline: 1.1708x; 1.1708x over previous
//
#include <hip/hip_runtime.h>
#include <hip/hip_bf16.h>
#include <math.h>

// ---------------------------------------------------------------------------
// PositionalAttentionPooling — MFMA branch GEMMs + MFMA attention weights
//   branch2: barrier-free MFMA -> tEU[NR][80], eWnU[NR][128]
//   node list: per-segment packed row<<6|pos (+ nodeSeg), product rows repeated
//   segsum3: gather over node list
//   coarse:  segmean @ Wc^T + bn -> cWcbf (bf16)
//   attw:    att[node] = Wa . sigmoid(eWnU+cWc+posWn)  via MFMA (no butterflies)
//   pool:    out[b] = (1/cnt) * sum att_i * emb_i      (pure FMA gather)
// ---------------------------------------------------------------------------

constexpr int D   = 128;
constexpr int DL  = 78;
constexpr int MSL = 50;
constexpr int RP  = 80;   // padded row stride for tEU

typedef __attribute__((ext_vector_type(8))) short bfrag8;   // 8 bf16 (4 VGPR)
typedef __attribute__((ext_vector_type(4))) float facc4;    // 4 f32 acc
typedef __attribute__((ext_vector_type(4))) short short4v;  // 8B

__device__ __forceinline__ float sigmoidf_(float x) {
    return 1.f / (1.f + __expf(-x));
}
__device__ __forceinline__ float ftanh(float x) {
    float e = __expf(2.f * x);
    return 1.f - 2.f * __builtin_amdgcn_rcpf(e + 1.f);
}
__device__ __forceinline__ float bs2f(short s) {
    unsigned u = ((unsigned)(unsigned short)s) << 16;
    return __builtin_bit_cast(float, u);
}
__device__ __forceinline__ short f2bs(float f) {
    return __builtin_bit_cast(short, __float2bfloat16(f));
}

// ---- swizzled LDS helpers (row stride 256B, XOR bits 4..6 by row&7) -------
__device__ __forceinline__ char* ldsAddr(__hip_bfloat16* base, int row, int byte_in_row) {
    return reinterpret_cast<char*>(base) + row * 256 + (byte_in_row ^ ((row & 7) << 4));
}
__device__ __forceinline__ bfrag8 ldsR16(const __hip_bfloat16* base, int row, int byte_in_row) {
    return *reinterpret_cast<const bfrag8*>(
        reinterpret_cast<const char*>(base) + row * 256 + (byte_in_row ^ ((row & 7) << 4)));
}
__device__ __forceinline__ short4v ldsR8(const __hip_bfloat16* base, int row, int byte_in_row) {
    return *reinterpret_cast<const short4v*>(
        reinterpret_cast<const char*>(base) + row * 256 + (byte_in_row ^ ((row & 7) << 4)));
}

__device__ __forceinline__ bfrag8 cvt8(float4 a, float4 b) {
    __hip_bfloat16 t[8] = {__float2bfloat16(a.x), __float2bfloat16(a.y),
                           __float2bfloat16(a.z), __float2bfloat16(a.w),
                           __float2bfloat16(b.x), __float2bfloat16(b.y),
                           __float2bfloat16(b.z), __float2bfloat16(b.w)};
    return *reinterpret_cast<bfrag8*>(t);
}

// --- tables: tpos = tanh(pos_table) [f32]; posWnbf = tpos @ Wn2^T [bf16]
__global__ __launch_bounds__(256) void k_tables2(
    const float* __restrict__ pos_table, const float* __restrict__ Wn,
    float* __restrict__ tpos, __hip_bfloat16* __restrict__ posWnbf) {
    __shared__ float tposL[MSL * MSL];
    int t = threadIdx.x;
    for (int o = t; o < MSL * MSL; o += 256) tposL[o] = tanhf(pos_table[o]);
    __syncthreads();
    if (blockIdx.x == 0)
        for (int o = t; o < MSL * MSL; o += 256) tpos[o] = tposL[o];
    for (int o = blockIdx.x * 256 + t; o < MSL * D; o += gridDim.x * 256) {
        int r = o >> 7, d = o & 127;
        float acc = 0.f;
        #pragma unroll 10
        for (int j = 0; j < MSL; ++j) acc += tposL[r * MSL + j] * Wn[d * D + DL + j];
        posWnbf[o] = __float2bfloat16(acc);
    }
}

// --- convW: bf16 weight tables (+ Wa)
__global__ __launch_bounds__(256) void k_convW(
    const float* __restrict__ Wq, const float* __restrict__ Wp, const float* __restrict__ Wn,
    const float* __restrict__ Wa,
    __hip_bfloat16* __restrict__ Wqbf, __hip_bfloat16* __restrict__ Wpbf,
    __hip_bfloat16* __restrict__ Wnbf, __hip_bfloat16* __restrict__ Wabf) {
    int i = blockIdx.x * 256 + threadIdx.x;
    if (i < 80 * 128) {
        int n = i >> 7;
        Wqbf[i] = __float2bfloat16((n < DL) ? Wq[i] : 0.f);
        Wpbf[i] = __float2bfloat16((n < DL) ? Wp[i] : 0.f);
    } else if (i < 80 * 128 + 128 * 128) {
        int o = i - 80 * 128;
        int j = o & 127;
        Wnbf[o] = __float2bfloat16((j < DL) ? Wn[o] : 0.f);
    } else if (i < 80 * 128 + 128 * 128 + 128) {
        int o = i - 80 * 128 - 128 * 128;
        Wabf[o] = __float2bfloat16(Wa[o]);
    }
}

// --- exclusive scan of cnt -> prodOff
__global__ void k_scanA(const int* __restrict__ cnt, int P, int* __restrict__ chunkSum) {
    __shared__ int s[256];
    int p = blockIdx.x * 256 + threadIdx.x;
    s[threadIdx.x] = (p < P) ? cnt[p] : 0;
    __syncthreads();
    for (int st = 128; st > 0; st >>= 1) {
        if (threadIdx.x < st) s[threadIdx.x] += s[threadIdx.x + st];
        __syncthreads();
    }
    if (threadIdx.x == 0) chunkSum[blockIdx.x] = s[0];
}
__global__ __launch_bounds__(1024) void k_scanB(
    const int* __restrict__ chunkSum, int nC, int* __restrict__ chunkOff) {
    __shared__ int s[1024];
    int t = threadIdx.x;
    int carry = 0;
    for (int base = 0; base < nC; base += 1024) {
        int v = (base + t < nC) ? chunkSum[base + t] : 0;
        s[t] = v;
        __syncthreads();
        for (int st = 1; st < 1024; st <<= 1) {
            int add = (t >= st) ? s[t - st] : 0;
            __syncthreads();
            s[t] += add;
            __syncthreads();
        }
        if (base + t < nC) chunkOff[base + t] = carry + s[t] - v;  // exclusive
        carry += s[1023];
        __syncthreads();
    }
}
__global__ void k_scanC(const int* __restrict__ cnt, int P, const int* __restrict__ chunkOff,
                        int* __restrict__ prodOff) {
    __shared__ int s[256];
    int t = threadIdx.x;
    int p = blockIdx.x * 256 + t;
    int v = (p < P) ? cnt[p] : 0;
    s[t] = v;
    __syncthreads();
    for (int st = 1; st < 256; st <<= 1) {
        int add = (t >= st) ? s[t - st] : 0;
        __syncthreads();
        s[t] += add;
        __syncthreads();
    }
    if (p < P) prodOff[p] = chunkOff[blockIdx.x] + s[t] - v;  // exclusive
}

// --- node count per segment (queries 1 each, products cnt each)
__global__ void k_cnt2(const int* __restrict__ qbatch, const int* __restrict__ pbatch,
                       const int* __restrict__ cnt, int NQ, int P, int* __restrict__ nodeCnt) {
    int i = blockIdx.x * 256 + threadIdx.x;
    if (i < NQ) {
        atomicAdd(&nodeCnt[qbatch[i]], 1);
    } else if (i < NQ + P) {
        int p = i - NQ;
        atomicAdd(&nodeCnt[pbatch[p]], cnt[p]);
    }
}
__global__ __launch_bounds__(1024) void k_scanSeg(
    const int* __restrict__ nodeCnt, int B, int* __restrict__ segOff, int* __restrict__ cursor) {
    __shared__ int s[1024];
    int t = threadIdx.x;
    int carry = 0;
    for (int base = 0; base < B; base += 1024) {
        int v = (base + t < B) ? nodeCnt[base + t] : 0;
        s[t] = v;
        __syncthreads();
        for (int st = 1; st < 1024; st <<= 1) {
            int add = (t >= st) ? s[t - st] : 0;
            __syncthreads();
            s[t] += add;
            __syncthreads();
        }
        if (base + t < B) {
            int e = carry + s[t] - v;
            segOff[base + t] = e;
            cursor[base + t] = e;
        }
        carry += s[1023];
        __syncthreads();
    }
    if (t == 0) segOff[B] = carry;
}
// --- node list: nodeIdx = row<<6|pos (product rows offset NQ, repeated), nodeSeg = b
__global__ void k_rank2(const int* __restrict__ qbatch, const int* __restrict__ pbatch,
                        const int* __restrict__ qpos, const int* __restrict__ ppos,
                        const int* __restrict__ cnt, const int* __restrict__ prodOff,
                        int NQ, int P, int* __restrict__ cursor,
                        int* __restrict__ nodeIdx, int* __restrict__ nodeSeg) {
    int i = blockIdx.x * 256 + threadIdx.x;
    if (i < NQ) {
        int b = qbatch[i];
        int slot = atomicAdd(&cursor[b], 1);
        nodeIdx[slot] = (i << 6) | qpos[i];
        nodeSeg[slot] = b;
    } else if (i < NQ + P) {
        int p = i - NQ;
        int b = pbatch[p];
        int c = cnt[p], off = prodOff[p];
        int slot = atomicAdd(&cursor[b], c);
        for (int j = 0; j < c; ++j) {
            nodeIdx[slot + j] = ((NQ + p) << 6) | ppos[off + j];
            nodeSeg[slot + j] = b;
        }
    }
}

// --- merged MFMA branch kernel: 64 rows/block, 4 waves, ZERO barriers
__global__ __launch_bounds__(256) void k_branch2(
    const float* __restrict__ qfeat, const float* __restrict__ pfeat,
    const __hip_bfloat16* __restrict__ Wqbf, const __hip_bfloat16* __restrict__ Wpbf,
    const float* __restrict__ bq, const float* __restrict__ bp,
    const __hip_bfloat16* __restrict__ Wnbf,
    int NQ, int P, int qBlocks,
    __hip_bfloat16* __restrict__ tEU, __hip_bfloat16* __restrict__ eWnU) {
    const bool isQ = (int)blockIdx.x < qBlocks;
    const int r0 = (isQ ? blockIdx.x : blockIdx.x - qBlocks) * 64;
    const float* feat = isQ ? qfeat : pfeat;
    const __hip_bfloat16* Wbf = isQ ? Wqbf : Wpbf;
    const float* bias = isQ ? bq : bp;
    const int Nrows = isQ ? NQ : P;
    const int rowBase = isQ ? 0 : NQ;

    __shared__ __hip_bfloat16 linL[64 * 128];
    __shared__ __hip_bfloat16 eWnL[64 * 128];
    int t = threadIdx.x;
    int l = t & 63, w = t >> 6;
    int lr = l & 15, lq = l >> 4;
    int am = w * 16 + lr;

    if (l < 16) {
        bfrag8 z = {0, 0, 0, 0, 0, 0, 0, 0};
        *reinterpret_cast<bfrag8*>(ldsAddr(linL, w * 16 + l, 160)) = z;
        *reinterpret_cast<bfrag8*>(ldsAddr(linL, w * 16 + l, 176)) = z;
    }

    int gra = r0 + am;
    const float* frow = &feat[(size_t)(gra < Nrows ? gra : Nrows - 1) * 128];
    bfrag8 a[4];
    #pragma unroll
    for (int kt = 0; kt < 4; ++kt) {
        float4 u = *reinterpret_cast<const float4*>(&frow[kt * 32 + lq * 8]);
        float4 v = *reinterpret_cast<const float4*>(&frow[kt * 32 + lq * 8 + 4]);
        a[kt] = cvt8(u, v);
    }

    facc4 c1[5];
    #pragma unroll
    for (int nt = 0; nt < 5; ++nt) { facc4 z = {0.f, 0.f, 0.f, 0.f}; c1[nt] = z; }
    #pragma unroll
    for (int nt = 0; nt < 5; ++nt) {
        #pragma unroll
        for (int kt = 0; kt < 4; ++kt) {
            bfrag8 b = *reinterpret_cast<const bfrag8*>(&Wbf[(nt * 16 + lr) * 128 + kt * 32 + lq * 8]);
            c1[nt] = __builtin_amdgcn_mfma_f32_16x16x32_bf16(a[kt], b, c1[nt], 0, 0, 0);
        }
    }

    #pragma unroll
    for (int nt = 0; nt < 5; ++nt) {
        int n = nt * 16 + lr;
        float bs = (n < DL) ? bias[n] : 0.f;
        #pragma unroll
        for (int j = 0; j < 4; ++j) {
            int m = w * 16 + lq * 4 + j;
            float tv = (n < DL) ? ftanh(c1[nt][j] + bs) : 0.f;
            *reinterpret_cast<__hip_bfloat16*>(ldsAddr(linL, m, 2 * n)) = __float2bfloat16(tv);
        }
    }

    {
        int r = w * 16 + (l >> 2), c = l & 3;
        int gr = r0 + r;
        #pragma unroll
        for (int j = 0; j < 5; ++j) {
            short4v v = ldsR8(linL, r, c * 40 + j * 8);
            if (gr < Nrows)
                *reinterpret_cast<short4v*>(&tEU[(size_t)(rowBase + gr) * RP + c * 20 + j * 4]) = v;
        }
    }

    bfrag8 a2[3];
    #pragma unroll
    for (int kt = 0; kt < 3; ++kt) a2[kt] = ldsR16(linL, am, kt * 64 + lq * 16);
    facc4 c2[8];
    #pragma unroll
    for (int nt = 0; nt < 8; ++nt) { facc4 z = {0.f, 0.f, 0.f, 0.f}; c2[nt] = z; }
    #pragma unroll
    for (int nt = 0; nt < 8; ++nt) {
        #pragma unroll
        for (int kt = 0; kt < 3; ++kt) {
            bfrag8 b = *reinterpret_cast<const bfrag8*>(&Wnbf[(nt * 16 + lr) * 128 + kt * 32 + lq * 8]);
            c2[nt] = __builtin_amdgcn_mfma_f32_16x16x32_bf16(a2[kt], b, c2[nt], 0, 0, 0);
        }
    }
    #pragma unroll
    for (int nt = 0; nt < 8; ++nt) {
        int d2 = nt * 16 + lr;
        #pragma unroll
        for (int j = 0; j < 4; ++j) {
            int m = w * 16 + lq * 4 + j;
            *reinterpret_cast<__hip_bfloat16*>(ldsAddr(eWnL, m, 2 * d2)) =
                __float2bfloat16(c2[nt][j]);
        }
    }
    {
        int r = w * 16 + (l >> 2), c = l & 3;
        int gr = r0 + r;
        #pragma unroll
        for (int j = 0; j < 4; ++j) {
            bfrag8 v = ldsR16(eWnL, r, c * 64 + j * 16);
            if (gr < Nrows)
                *reinterpret_cast<bfrag8*>(&eWnU[(size_t)(rowBase + gr) * 128 + c * 32 + j * 8]) = v;
        }
    }
}

// --- segsum via node list gather: block(128) per segment
__global__ __launch_bounds__(128) void k_segsum3(
    const __hip_bfloat16* __restrict__ tEU, const int* __restrict__ nodeIdx,
    const int* __restrict__ segOff, const float* __restrict__ tpos, int B,
    float* __restrict__ segsum, float* __restrict__ segcnt) {
    int b = blockIdx.x, t = threadIdx.x;
    int s0 = segOff[b], s1 = segOff[b + 1];
    float acc = 0.f;
    if (t < DL) {
        for (int i = s0; i < s1; i += 4) {
            #pragma unroll
            for (int j = 0; j < 4; ++j) {
                if (i + j < s1) {
                    int row = nodeIdx[i + j] >> 6;
                    acc += __bfloat162float(tEU[(size_t)row * RP + t]);
                }
            }
        }
        segsum[(size_t)b * D + t] = acc;
    } else {
        int k = t - DL;  // 0..49
        for (int i = s0; i < s1; i += 4) {
            #pragma unroll
            for (int j = 0; j < 4; ++j) {
                if (i + j < s1) {
                    int pos = nodeIdx[i + j] & 63;
                    acc += tpos[pos * MSL + k];
                }
            }
        }
        segsum[(size_t)b * D + DL + k] = acc;
        if (k == 0) segcnt[b] = (float)(s1 - s0);
    }
}

// --- coarse = segsum/cnt ; cWcbf = bf16(coarse @ Wc^T + bn)
__global__ __launch_bounds__(256) void k_coarse(
    const float* __restrict__ segsum, const float* __restrict__ segcnt,
    const float* __restrict__ Wc, const float* __restrict__ bn, int B,
    __hip_bfloat16* __restrict__ cWcbf) {
    __shared__ __hip_bfloat16 WcL[128 * 130];
    __shared__ float cL[16 * 128];
    int t = threadIdx.x;
    int b0 = blockIdx.x * 16;
    for (int o = t; o < D * D; o += 256) {
        int d = o >> 7, k = o & 127;
        WcL[d * 130 + k] = __float2bfloat16(Wc[o]);
    }
    for (int o = t; o < 16 * D; o += 256) {
        int bb = o >> 7, d = o & 127;
        int b = b0 + bb;
        cL[o] = (b < B) ? segsum[(size_t)b * D + d] / fmaxf(segcnt[b], 1.f) : 0.f;
    }
    __syncthreads();
    for (int o = t; o < 16 * D; o += 256) {
        int bb = o >> 7, d = o & 127;
        int b = b0 + bb;
        if (b >= B) continue;
        float acc = bn[d];
        const float* cr = &cL[bb * 128];
        const __hip_bfloat16* wr = &WcL[d * 130];
        #pragma unroll 8
        for (int j = 0; j < D; ++j) acc += cr[j] * __bfloat162float(wr[j]);
        cWcbf[(size_t)b * D + d] = __float2bfloat16(acc);
    }
}

// --- attention weights via MFMA: 64 nodes/block, 16 per wave, NO cross-lane ops
__global__ __launch_bounds__(256) void k_attw(
    const __hip_bfloat16* __restrict__ eWnU, const __hip_bfloat16* __restrict__ cWcbf,
    const __hip_bfloat16* __restrict__ posWnbf, const __hip_bfloat16* __restrict__ Wabf,
    const int* __restrict__ nodeIdx, const int* __restrict__ nodeSeg,
    int NN, float* __restrict__ att) {
    int t = threadIdx.x;
    int l = t & 63, w = t >> 6;
    int lr = l & 15, lq = l >> 4;
    int i0 = blockIdx.x * 64 + w * 16;
    int n = i0 + lr;
    bool on = n < NN;
    int pk = on ? nodeIdx[n] : 0;
    int b  = on ? nodeSeg[n] : 0;
    int row = pk >> 6, pos = pk & 63;

    facc4 c = {0.f, 0.f, 0.f, 0.f};
    #pragma unroll
    for (int kt = 0; kt < 4; ++kt) {
        int col = kt * 32 + lq * 8;
        bfrag8 e  = *reinterpret_cast<const bfrag8*>(&eWnU[(size_t)row * D + col]);
        bfrag8 cw = *reinterpret_cast<const bfrag8*>(&cWcbf[(size_t)b * D + col]);
        bfrag8 pw = *reinterpret_cast<const bfrag8*>(&posWnbf[pos * D + col]);
        bfrag8 s;
        #pragma unroll
        for (int j = 0; j < 8; ++j) {
            float z = bs2f(e[j]) + bs2f(cw[j]) + bs2f(pw[j]);
            s[j] = f2bs(sigmoidf_(z));
        }
        bfrag8 wa = *reinterpret_cast<const bfrag8*>(&Wabf[col]);
        c = __builtin_amdgcn_mfma_f32_16x16x32_bf16(s, wa, c, 0, 0, 0);
    }
    // C[m][n]: lane(lq,lr) holds rows m=lq*4+j, col n=lr (all cols equal)
    if (lr == 0) {
        #pragma unroll
        for (int j = 0; j < 4; ++j) {
            int m = i0 + lq * 4 + j;
            if (m < NN) att[m] = c[j];
        }
    }
}

// --- pool: wave per segment, out[b] = (1/cnt) * sum att_i * emb_i
__global__ __launch_bounds__(256) void k_pool(
    const __hip_bfloat16* __restrict__ tEU, const float* __restrict__ att,
    const float* __restrict__ tpos, const int* __restrict__ nodeIdx,
    const int* __restrict__ segOff, const float* __restrict__ segcnt,
    int B, float* __restrict__ out) {
    int wv = threadIdx.x >> 6, l = threadIdx.x & 63;
    int b = blockIdx.x * 4 + wv;
    if (b >= B) return;
    int s0 = segOff[b], s1 = segOff[b + 1];
    float acc0 = 0.f, acc1 = 0.f;

    for (int i = s0; i < s1; i += 4) {
        float a[4];
        int row[4], pos[4];
        #pragma unroll
        for (int j = 0; j < 4; ++j) {
            bool on = (i + j) < s1;
            int pk = on ? nodeIdx[i + j] : 0;
            a[j] = on ? att[i + j] : 0.f;
            row[j] = pk >> 6;
            pos[j] = pk & 63;
        }
        #pragma unroll
        for (int j = 0; j < 4; ++j) {
            acc0 += a[j] * __bfloat162float(tEU[(size_t)row[j] * RP + l]);
            if (l < 14) acc1 += a[j] * __bfloat162float(tEU[(size_t)row[j] * RP + 64 + l]);
            else        acc1 += a[j] * tpos[pos[j] * MSL + (l - 14)];
        }
    }

    float inv = 1.f / fmaxf(segcnt[b], 1.f);
    out[(size_t)b * D + l] = acc0 * inv;
    out[(size_t)b * D + 64 + l] = acc1 * inv;
}

extern "C" void kernel_launch(void* const* d_in, const int* in_sizes, int n_in,
                              void* d_out, int out_size, void* d_ws, size_t ws_size,
                              hipStream_t stream) {
    const float* query_feat   = (const float*)d_in[0];
    const float* product_feat = (const float*)d_in[1];
    const float* Wq = (const float*)d_in[2];
    const float* bq = (const float*)d_in[3];
    const float* Wp = (const float*)d_in[4];
    const float* bp = (const float*)d_in[5];
    const float* pos_table = (const float*)d_in[6];
    const float* Wn = (const float*)d_in[7];
    const float* bn = (const float*)d_in[8];
    const float* Wc = (const float*)d_in[9];
    const float* Wa = (const float*)d_in[10];
    const int* qpos   = (const int*)d_in[11];
    const int* ppos   = (const int*)d_in[12];
    const int* qbatch = (const int*)d_in[13];
    const int* pbatch = (const int*)d_in[14];
    const int* cnt    = (const int*)d_in[15];

    int NQ = in_sizes[11];
    int T  = in_sizes[12];   // total product nodes
    int P  = in_sizes[15];
    int B  = out_size / D;
    int NR = NQ + P;         // rows in unified tables
    int NN = NQ + T;         // total node-list entries
    float* out = (float*)d_out;

    // workspace layout (256B aligned chunks)
    char* w = (char*)d_ws;
    size_t off = 0;
    auto take = [&](size_t bytes) -> char* {
        char* p = w + off;
        off = (off + bytes + 255) & ~(size_t)255;
        return p;
    };
    int*   nodeCnt = (int*)  take((size_t)B * 4);
    size_t zeroBytes = off;
    float* segsum   = (float*)take((size_t)B * D * 4);
    float* segcnt   = (float*)take((size_t)B * 4);
    float* tpos  = (float*)take(MSL * MSL * 4);
    __hip_bfloat16* posWnbf = (__hip_bfloat16*)take(MSL * D * 2);
    __hip_bfloat16* cWcbf   = (__hip_bfloat16*)take((size_t)B * D * 2);
    __hip_bfloat16* Wqbf = (__hip_bfloat16*)take(80 * 128 * 2);
    __hip_bfloat16* Wpbf = (__hip_bfloat16*)take(80 * 128 * 2);
    __hip_bfloat16* Wnbf = (__hip_bfloat16*)take(128 * 128 * 2);
    __hip_bfloat16* Wabf = (__hip_bfloat16*)take(128 * 2);
    int nC = (P + 255) / 256;
    int* chunkSum = (int*)take((size_t)nC * 4);
    int* chunkOff = (int*)take((size_t)nC * 4);
    int* prodOff  = (int*)take((size_t)P * 4);
    int* segOffA  = (int*)take((size_t)(B + 1) * 4);
    int* cursor   = (int*)take((size_t)B * 4);
    int* nodeIdx  = (int*)take((size_t)NN * 4);
    int* nodeSeg  = (int*)take((size_t)NN * 4);
    float* att    = (float*)take((size_t)NN * 4);
    __hip_bfloat16* tEU  = (__hip_bfloat16*)take((size_t)NR * RP * 2);
    __hip_bfloat16* eWnU = (__hip_bfloat16*)take((size_t)NR * D * 2);
    (void)ws_size; (void)n_in;

    hipMemsetAsync(nodeCnt, 0, zeroBytes, stream);

    hipLaunchKernelGGL(k_tables2, dim3(8), dim3(256), 0, stream, pos_table, Wn, tpos, posWnbf);
    hipLaunchKernelGGL(k_convW, dim3((80 * 128 + 128 * 128 + 128 + 255) / 256), dim3(256), 0,
                       stream, Wq, Wp, Wn, Wa, Wqbf, Wpbf, Wnbf, Wabf);
    hipLaunchKernelGGL(k_scanA, dim3(nC), dim3(256), 0, stream, cnt, P, chunkSum);
    hipLaunchKernelGGL(k_scanB, dim3(1), dim3(1024), 0, stream, chunkSum, nC, chunkOff);
    hipLaunchKernelGGL(k_scanC, dim3(nC), dim3(256), 0, stream, cnt, P, chunkOff, prodOff);

    hipLaunchKernelGGL(k_cnt2, dim3((NR + 255) / 256), dim3(256), 0, stream,
                       qbatch, pbatch, cnt, NQ, P, nodeCnt);
    hipLaunchKernelGGL(k_scanSeg, dim3(1), dim3(1024), 0, stream, nodeCnt, B, segOffA, cursor);
    hipLaunchKernelGGL(k_rank2, dim3((NR + 255) / 256), dim3(256), 0, stream,
                       qbatch, pbatch, qpos, ppos, cnt, prodOff, NQ, P, cursor,
                       nodeIdx, nodeSeg);

    int qBlocks = (NQ + 63) / 64, pBlocksBr = (P + 63) / 64;
    hipLaunchKernelGGL(k_branch2, dim3(qBlocks + pBlocksBr), dim3(256), 0, stream,
                       query_feat, product_feat, Wqbf, Wpbf, bq, bp, Wnbf,
                       NQ, P, qBlocks, tEU, eWnU);

    hipLaunchKernelGGL(k_segsum3, dim3(B), dim3(128), 0, stream,
                       tEU, nodeIdx, segOffA, tpos, B, segsum, segcnt);
    hipLaunchKernelGGL(k_coarse, dim3((B + 15) / 16), dim3(256), 0, stream,
                       segsum, segcnt, Wc, bn, B, cWcbf);

    hipLaunchKernelGGL(k_attw, dim3((NN + 63) / 64), dim3(256), 0, stream,
                       eWnU, cWcbf, posWnbf, Wabf, nodeIdx, nodeSeg, NN, att);
    hipLaunchKernelGGL(k_pool, dim3((B + 3) / 4), dim3(256), 0, stream,
                       tEU, att, tpos, nodeIdx, segOffA, segcnt, B, out);
}

// Round 11
// 312.529 us; speedup vs baseline: 1.2091x; 1.0327x over previous
//
#include <hip/hip_runtime.h>
#include <hip/hip_bf16.h>
#include <math.h>

// ---------------------------------------------------------------------------
// PositionalAttentionPooling — MFMA branch GEMMs + MFMA attention weights
//   branch3: grid-stride barrier-light MFMA; Wn staged in LDS; A prefetch;
//            lin/eWn share one wave-local LDS stripe
//   node list: per-segment packed row<<6|pos (+ nodeSeg)
//   segsum3: gather over node list
//   coarse:  segmean @ Wc^T + bn -> cWcbf (bf16)
//   attw:    att[node] = Wa . sigmoid(eWnU+cWc+posWn)  via MFMA
//   pool:    out[b] = (1/cnt) * sum att_i * emb_i
// ---------------------------------------------------------------------------

constexpr int D   = 128;
constexpr int DL  = 78;
constexpr int MSL = 50;
constexpr int RP  = 80;   // padded row stride for tEU

typedef __attribute__((ext_vector_type(8))) short bfrag8;   // 8 bf16 (4 VGPR)
typedef __attribute__((ext_vector_type(4))) float facc4;    // 4 f32 acc
typedef __attribute__((ext_vector_type(4))) short short4v;  // 8B

__device__ __forceinline__ float sigmoidf_(float x) {
    return 1.f / (1.f + __expf(-x));
}
__device__ __forceinline__ float ftanh(float x) {
    float e = __expf(2.f * x);
    return 1.f - 2.f * __builtin_amdgcn_rcpf(e + 1.f);
}
__device__ __forceinline__ float bs2f(short s) {
    unsigned u = ((unsigned)(unsigned short)s) << 16;
    return __builtin_bit_cast(float, u);
}
__device__ __forceinline__ short f2bs(float f) {
    return __builtin_bit_cast(short, __float2bfloat16(f));
}

// ---- swizzled LDS helpers (row stride 256B, XOR bits 4..6 by row&7) -------
__device__ __forceinline__ char* ldsAddr(__hip_bfloat16* base, int row, int byte_in_row) {
    return reinterpret_cast<char*>(base) + row * 256 + (byte_in_row ^ ((row & 7) << 4));
}
__device__ __forceinline__ bfrag8 ldsR16(const __hip_bfloat16* base, int row, int byte_in_row) {
    return *reinterpret_cast<const bfrag8*>(
        reinterpret_cast<const char*>(base) + row * 256 + (byte_in_row ^ ((row & 7) << 4)));
}
__device__ __forceinline__ short4v ldsR8(const __hip_bfloat16* base, int row, int byte_in_row) {
    return *reinterpret_cast<const short4v*>(
        reinterpret_cast<const char*>(base) + row * 256 + (byte_in_row ^ ((row & 7) << 4)));
}

__device__ __forceinline__ bfrag8 cvt8(float4 a, float4 b) {
    __hip_bfloat16 t[8] = {__float2bfloat16(a.x), __float2bfloat16(a.y),
                           __float2bfloat16(a.z), __float2bfloat16(a.w),
                           __float2bfloat16(b.x), __float2bfloat16(b.y),
                           __float2bfloat16(b.z), __float2bfloat16(b.w)};
    return *reinterpret_cast<bfrag8*>(t);
}

// --- tables: tpos = tanh(pos_table) [f32]; posWnbf = tpos @ Wn2^T [bf16]
__global__ __launch_bounds__(256) void k_tables2(
    const float* __restrict__ pos_table, const float* __restrict__ Wn,
    float* __restrict__ tpos, __hip_bfloat16* __restrict__ posWnbf) {
    __shared__ float tposL[MSL * MSL];
    int t = threadIdx.x;
    for (int o = t; o < MSL * MSL; o += 256) tposL[o] = tanhf(pos_table[o]);
    __syncthreads();
    if (blockIdx.x == 0)
        for (int o = t; o < MSL * MSL; o += 256) tpos[o] = tposL[o];
    for (int o = blockIdx.x * 256 + t; o < MSL * D; o += gridDim.x * 256) {
        int r = o >> 7, d = o & 127;
        float acc = 0.f;
        #pragma unroll 10
        for (int j = 0; j < MSL; ++j) acc += tposL[r * MSL + j] * Wn[d * D + DL + j];
        posWnbf[o] = __float2bfloat16(acc);
    }
}

// --- convW: bf16 weight tables (+ Wa)
__global__ __launch_bounds__(256) void k_convW(
    const float* __restrict__ Wq, const float* __restrict__ Wp, const float* __restrict__ Wn,
    const float* __restrict__ Wa,
    __hip_bfloat16* __restrict__ Wqbf, __hip_bfloat16* __restrict__ Wpbf,
    __hip_bfloat16* __restrict__ Wnbf, __hip_bfloat16* __restrict__ Wabf) {
    int i = blockIdx.x * 256 + threadIdx.x;
    if (i < 80 * 128) {
        int n = i >> 7;
        Wqbf[i] = __float2bfloat16((n < DL) ? Wq[i] : 0.f);
        Wpbf[i] = __float2bfloat16((n < DL) ? Wp[i] : 0.f);
    } else if (i < 80 * 128 + 128 * 128) {
        int o = i - 80 * 128;
        int j = o & 127;
        Wnbf[o] = __float2bfloat16((j < DL) ? Wn[o] : 0.f);
    } else if (i < 80 * 128 + 128 * 128 + 128) {
        int o = i - 80 * 128 - 128 * 128;
        Wabf[o] = __float2bfloat16(Wa[o]);
    }
}

// --- exclusive scan of cnt -> prodOff
__global__ void k_scanA(const int* __restrict__ cnt, int P, int* __restrict__ chunkSum) {
    __shared__ int s[256];
    int p = blockIdx.x * 256 + threadIdx.x;
    s[threadIdx.x] = (p < P) ? cnt[p] : 0;
    __syncthreads();
    for (int st = 128; st > 0; st >>= 1) {
        if (threadIdx.x < st) s[threadIdx.x] += s[threadIdx.x + st];
        __syncthreads();
    }
    if (threadIdx.x == 0) chunkSum[blockIdx.x] = s[0];
}
__global__ __launch_bounds__(1024) void k_scanB(
    const int* __restrict__ chunkSum, int nC, int* __restrict__ chunkOff) {
    __shared__ int s[1024];
    int t = threadIdx.x;
    int carry = 0;
    for (int base = 0; base < nC; base += 1024) {
        int v = (base + t < nC) ? chunkSum[base + t] : 0;
        s[t] = v;
        __syncthreads();
        for (int st = 1; st < 1024; st <<= 1) {
            int add = (t >= st) ? s[t - st] : 0;
            __syncthreads();
            s[t] += add;
            __syncthreads();
        }
        if (base + t < nC) chunkOff[base + t] = carry + s[t] - v;  // exclusive
        carry += s[1023];
        __syncthreads();
    }
}
__global__ void k_scanC(const int* __restrict__ cnt, int P, const int* __restrict__ chunkOff,
                        int* __restrict__ prodOff) {
    __shared__ int s[256];
    int t = threadIdx.x;
    int p = blockIdx.x * 256 + t;
    int v = (p < P) ? cnt[p] : 0;
    s[t] = v;
    __syncthreads();
    for (int st = 1; st < 256; st <<= 1) {
        int add = (t >= st) ? s[t - st] : 0;
        __syncthreads();
        s[t] += add;
        __syncthreads();
    }
    if (p < P) prodOff[p] = chunkOff[blockIdx.x] + s[t] - v;  // exclusive
}

// --- node count per segment (queries 1 each, products cnt each)
__global__ void k_cnt2(const int* __restrict__ qbatch, const int* __restrict__ pbatch,
                       const int* __restrict__ cnt, int NQ, int P, int* __restrict__ nodeCnt) {
    int i = blockIdx.x * 256 + threadIdx.x;
    if (i < NQ) {
        atomicAdd(&nodeCnt[qbatch[i]], 1);
    } else if (i < NQ + P) {
        int p = i - NQ;
        atomicAdd(&nodeCnt[pbatch[p]], cnt[p]);
    }
}
__global__ __launch_bounds__(1024) void k_scanSeg(
    const int* __restrict__ nodeCnt, int B, int* __restrict__ segOff, int* __restrict__ cursor) {
    __shared__ int s[1024];
    int t = threadIdx.x;
    int carry = 0;
    for (int base = 0; base < B; base += 1024) {
        int v = (base + t < B) ? nodeCnt[base + t] : 0;
        s[t] = v;
        __syncthreads();
        for (int st = 1; st < 1024; st <<= 1) {
            int add = (t >= st) ? s[t - st] : 0;
            __syncthreads();
            s[t] += add;
            __syncthreads();
        }
        if (base + t < B) {
            int e = carry + s[t] - v;
            segOff[base + t] = e;
            cursor[base + t] = e;
        }
        carry += s[1023];
        __syncthreads();
    }
    if (t == 0) segOff[B] = carry;
}
// --- node list: nodeIdx = row<<6|pos (product rows offset NQ, repeated), nodeSeg = b
__global__ void k_rank2(const int* __restrict__ qbatch, const int* __restrict__ pbatch,
                        const int* __restrict__ qpos, const int* __restrict__ ppos,
                        const int* __restrict__ cnt, const int* __restrict__ prodOff,
                        int NQ, int P, int* __restrict__ cursor,
                        int* __restrict__ nodeIdx, int* __restrict__ nodeSeg) {
    int i = blockIdx.x * 256 + threadIdx.x;
    if (i < NQ) {
        int b = qbatch[i];
        int slot = atomicAdd(&cursor[b], 1);
        nodeIdx[slot] = (i << 6) | qpos[i];
        nodeSeg[slot] = b;
    } else if (i < NQ + P) {
        int p = i - NQ;
        int b = pbatch[p];
        int c = cnt[p], off = prodOff[p];
        int slot = atomicAdd(&cursor[b], c);
        for (int j = 0; j < c; ++j) {
            nodeIdx[slot + j] = ((NQ + p) << 6) | ppos[off + j];
            nodeSeg[slot + j] = b;
        }
    }
}

// --- grid-stride MFMA branch kernel: Wn in LDS, A prefetch, shared stripe
__global__ __launch_bounds__(256) void k_branch3(
    const float* __restrict__ qfeat, const float* __restrict__ pfeat,
    const __hip_bfloat16* __restrict__ Wqbf, const __hip_bfloat16* __restrict__ Wpbf,
    const float* __restrict__ bq, const float* __restrict__ bp,
    const __hip_bfloat16* __restrict__ Wnbf,
    int NQ, int P, int nTilesQ, int nTiles,
    __hip_bfloat16* __restrict__ tEU, __hip_bfloat16* __restrict__ eWnU) {
    __shared__ __hip_bfloat16 sL[64 * 128];    // 16KB stripe: lin, then eWn overlay
    __shared__ __hip_bfloat16 WnL[128 * 128];  // 32KB swizzled Wn1

    int t = threadIdx.x;
    int l = t & 63, w = t >> 6;
    int lr = l & 15, lq = l >> 4;
    int am = w * 16 + lr;

    // stage Wn1 -> LDS (swizzled), once per block
    for (int i = t; i < 128 * 16; i += 256) {
        int row = i >> 4, chunk = i & 15;
        bfrag8 v = *reinterpret_cast<const bfrag8*>(&Wnbf[row * 128 + chunk * 8]);
        *reinterpret_cast<bfrag8*>(ldsAddr(WnL, row, chunk * 16)) = v;
    }
    __syncthreads();

    auto tileFrow = [&](int tl) -> const float* {
        bool iq = tl < nTilesQ;
        int r0 = (iq ? tl : tl - nTilesQ) * 64;
        const float* f = iq ? qfeat : pfeat;
        int Nr = iq ? NQ : P;
        int gr = r0 + am;
        return &f[(size_t)(gr < Nr ? gr : Nr - 1) * 128];
    };

    int tile = blockIdx.x;
    float4 uN[4], vN[4];
    if (tile < nTiles) {
        const float* fr = tileFrow(tile);
        #pragma unroll
        for (int kt = 0; kt < 4; ++kt) {
            uN[kt] = *reinterpret_cast<const float4*>(&fr[kt * 32 + lq * 8]);
            vN[kt] = *reinterpret_cast<const float4*>(&fr[kt * 32 + lq * 8 + 4]);
        }
    }

    for (; tile < nTiles; tile += gridDim.x) {
        const bool isQ = tile < nTilesQ;
        const int r0 = (isQ ? tile : tile - nTilesQ) * 64;
        const __hip_bfloat16* Wbf = isQ ? Wqbf : Wpbf;
        const float* bias = isQ ? bq : bp;
        const int Nrows = isQ ? NQ : P;
        const int rowBase = isQ ? 0 : NQ;

        // convert prefetched A
        bfrag8 a[4];
        #pragma unroll
        for (int kt = 0; kt < 4; ++kt) a[kt] = cvt8(uN[kt], vN[kt]);

        // re-zero K-pad cols [80,96) of stripe (clobbered by prev tile's eWn)
        if (l < 16) {
            bfrag8 z = {0, 0, 0, 0, 0, 0, 0, 0};
            *reinterpret_cast<bfrag8*>(ldsAddr(sL, w * 16 + l, 160)) = z;
            *reinterpret_cast<bfrag8*>(ldsAddr(sL, w * 16 + l, 176)) = z;
        }

        // phase1: C1[64,80] = feat @ Wbf^T  (B from global, L1-hot)
        facc4 c1[5];
        #pragma unroll
        for (int nt = 0; nt < 5; ++nt) { facc4 z = {0.f, 0.f, 0.f, 0.f}; c1[nt] = z; }
        #pragma unroll
        for (int nt = 0; nt < 5; ++nt) {
            #pragma unroll
            for (int kt = 0; kt < 4; ++kt) {
                bfrag8 b = *reinterpret_cast<const bfrag8*>(&Wbf[(nt * 16 + lr) * 128 + kt * 32 + lq * 8]);
                c1[nt] = __builtin_amdgcn_mfma_f32_16x16x32_bf16(a[kt], b, c1[nt], 0, 0, 0);
            }
        }

        // prefetch next tile's A (hides HBM latency under epilogue+phase2)
        int tnext = tile + gridDim.x;
        if (tnext < nTiles) {
            const float* fr = tileFrow(tnext);
            #pragma unroll
            for (int kt = 0; kt < 4; ++kt) {
                uN[kt] = *reinterpret_cast<const float4*>(&fr[kt * 32 + lq * 8]);
                vN[kt] = *reinterpret_cast<const float4*>(&fr[kt * 32 + lq * 8 + 4]);
            }
        }

        // epilogue1: tanh(+bias) -> stripe rows (wave-local)
        #pragma unroll
        for (int nt = 0; nt < 5; ++nt) {
            int n = nt * 16 + lr;
            float bs = (n < DL) ? bias[n] : 0.f;
            #pragma unroll
            for (int j = 0; j < 4; ++j) {
                int m = w * 16 + lq * 4 + j;
                float tv = (n < DL) ? ftanh(c1[nt][j] + bs) : 0.f;
                *reinterpret_cast<__hip_bfloat16*>(ldsAddr(sL, m, 2 * n)) = __float2bfloat16(tv);
            }
        }

        // copy lin -> tEU (wave-local 8B)
        {
            int r = w * 16 + (l >> 2), c = l & 3;
            int gr = r0 + r;
            #pragma unroll
            for (int j = 0; j < 5; ++j) {
                short4v v = ldsR8(sL, r, c * 40 + j * 8);
                if (gr < Nrows)
                    *reinterpret_cast<short4v*>(&tEU[(size_t)(rowBase + gr) * RP + c * 20 + j * 4]) = v;
            }
        }

        // phase2: C2[64,128] = lin[64,96] @ Wn1^T  (A from stripe, B from LDS)
        bfrag8 a2[3];
        #pragma unroll
        for (int kt = 0; kt < 3; ++kt) a2[kt] = ldsR16(sL, am, kt * 64 + lq * 16);
        facc4 c2[8];
        #pragma unroll
        for (int nt = 0; nt < 8; ++nt) { facc4 z = {0.f, 0.f, 0.f, 0.f}; c2[nt] = z; }
        #pragma unroll
        for (int nt = 0; nt < 8; ++nt) {
            #pragma unroll
            for (int kt = 0; kt < 3; ++kt) {
                bfrag8 b = ldsR16(WnL, nt * 16 + lr, kt * 64 + lq * 16);
                c2[nt] = __builtin_amdgcn_mfma_f32_16x16x32_bf16(a2[kt], b, c2[nt], 0, 0, 0);
            }
        }

        // stage eWn into stripe (overlay; lin dead), then copy out 16B
        #pragma unroll
        for (int nt = 0; nt < 8; ++nt) {
            int d2 = nt * 16 + lr;
            #pragma unroll
            for (int j = 0; j < 4; ++j) {
                int m = w * 16 + lq * 4 + j;
                *reinterpret_cast<__hip_bfloat16*>(ldsAddr(sL, m, 2 * d2)) =
                    __float2bfloat16(c2[nt][j]);
            }
        }
        {
            int r = w * 16 + (l >> 2), c = l & 3;
            int gr = r0 + r;
            #pragma unroll
            for (int j = 0; j < 4; ++j) {
                bfrag8 v = ldsR16(sL, r, c * 64 + j * 16);
                if (gr < Nrows)
                    *reinterpret_cast<bfrag8*>(&eWnU[(size_t)(rowBase + gr) * 128 + c * 32 + j * 8]) = v;
            }
        }
    }
}

// --- segsum via node list gather: block(128) per segment
__global__ __launch_bounds__(128) void k_segsum3(
    const __hip_bfloat16* __restrict__ tEU, const int* __restrict__ nodeIdx,
    const int* __restrict__ segOff, const float* __restrict__ tpos, int B,
    float* __restrict__ segsum, float* __restrict__ segcnt) {
    int b = blockIdx.x, t = threadIdx.x;
    int s0 = segOff[b], s1 = segOff[b + 1];
    float acc = 0.f;
    if (t < DL) {
        for (int i = s0; i < s1; i += 4) {
            #pragma unroll
            for (int j = 0; j < 4; ++j) {
                if (i + j < s1) {
                    int row = nodeIdx[i + j] >> 6;
                    acc += __bfloat162float(tEU[(size_t)row * RP + t]);
                }
            }
        }
        segsum[(size_t)b * D + t] = acc;
    } else {
        int k = t - DL;  // 0..49
        for (int i = s0; i < s1; i += 4) {
            #pragma unroll
            for (int j = 0; j < 4; ++j) {
                if (i + j < s1) {
                    int pos = nodeIdx[i + j] & 63;
                    acc += tpos[pos * MSL + k];
                }
            }
        }
        segsum[(size_t)b * D + DL + k] = acc;
        if (k == 0) segcnt[b] = (float)(s1 - s0);
    }
}

// --- coarse = segsum/cnt ; cWcbf = bf16(coarse @ Wc^T + bn)
__global__ __launch_bounds__(256) void k_coarse(
    const float* __restrict__ segsum, const float* __restrict__ segcnt,
    const float* __restrict__ Wc, const float* __restrict__ bn, int B,
    __hip_bfloat16* __restrict__ cWcbf) {
    __shared__ __hip_bfloat16 WcL[128 * 130];
    __shared__ float cL[16 * 128];
    int t = threadIdx.x;
    int b0 = blockIdx.x * 16;
    for (int o = t; o < D * D; o += 256) {
        int d = o >> 7, k = o & 127;
        WcL[d * 130 + k] = __float2bfloat16(Wc[o]);
    }
    for (int o = t; o < 16 * D; o += 256) {
        int bb = o >> 7, d = o & 127;
        int b = b0 + bb;
        cL[o] = (b < B) ? segsum[(size_t)b * D + d] / fmaxf(segcnt[b], 1.f) : 0.f;
    }
    __syncthreads();
    for (int o = t; o < 16 * D; o += 256) {
        int bb = o >> 7, d = o & 127;
        int b = b0 + bb;
        if (b >= B) continue;
        float acc = bn[d];
        const float* cr = &cL[bb * 128];
        const __hip_bfloat16* wr = &WcL[d * 130];
        #pragma unroll 8
        for (int j = 0; j < D; ++j) acc += cr[j] * __bfloat162float(wr[j]);
        cWcbf[(size_t)b * D + d] = __float2bfloat16(acc);
    }
}

// --- attention weights via MFMA: 64 nodes/block, 16 per wave, NO cross-lane ops
__global__ __launch_bounds__(256) void k_attw(
    const __hip_bfloat16* __restrict__ eWnU, const __hip_bfloat16* __restrict__ cWcbf,
    const __hip_bfloat16* __restrict__ posWnbf, const __hip_bfloat16* __restrict__ Wabf,
    const int* __restrict__ nodeIdx, const int* __restrict__ nodeSeg,
    int NN, float* __restrict__ att) {
    int t = threadIdx.x;
    int l = t & 63, w = t >> 6;
    int lr = l & 15, lq = l >> 4;
    int i0 = blockIdx.x * 64 + w * 16;
    int n = i0 + lr;
    bool on = n < NN;
    int pk = on ? nodeIdx[n] : 0;
    int b  = on ? nodeSeg[n] : 0;
    int row = pk >> 6, pos = pk & 63;

    facc4 c = {0.f, 0.f, 0.f, 0.f};
    #pragma unroll
    for (int kt = 0; kt < 4; ++kt) {
        int col = kt * 32 + lq * 8;
        bfrag8 e  = *reinterpret_cast<const bfrag8*>(&eWnU[(size_t)row * D + col]);
        bfrag8 cw = *reinterpret_cast<const bfrag8*>(&cWcbf[(size_t)b * D + col]);
        bfrag8 pw = *reinterpret_cast<const bfrag8*>(&posWnbf[pos * D + col]);
        bfrag8 s;
        #pragma unroll
        for (int j = 0; j < 8; ++j) {
            float z = bs2f(e[j]) + bs2f(cw[j]) + bs2f(pw[j]);
            s[j] = f2bs(sigmoidf_(z));
        }
        bfrag8 wa = *reinterpret_cast<const bfrag8*>(&Wabf[col]);
        c = __builtin_amdgcn_mfma_f32_16x16x32_bf16(s, wa, c, 0, 0, 0);
    }
    if (lr == 0) {
        #pragma unroll
        for (int j = 0; j < 4; ++j) {
            int m = i0 + lq * 4 + j;
            if (m < NN) att[m] = c[j];
        }
    }
}

// --- pool: wave per segment, out[b] = (1/cnt) * sum att_i * emb_i
__global__ __launch_bounds__(256) void k_pool(
    const __hip_bfloat16* __restrict__ tEU, const float* __restrict__ att,
    const float* __restrict__ tpos, const int* __restrict__ nodeIdx,
    const int* __restrict__ segOff, const float* __restrict__ segcnt,
    int B, float* __restrict__ out) {
    int wv = threadIdx.x >> 6, l = threadIdx.x & 63;
    int b = blockIdx.x * 4 + wv;
    if (b >= B) return;
    int s0 = segOff[b], s1 = segOff[b + 1];
    float acc0 = 0.f, acc1 = 0.f;

    for (int i = s0; i < s1; i += 8) {
        float a[8];
        int row[8], pos[8];
        #pragma unroll
        for (int j = 0; j < 8; ++j) {
            bool on = (i + j) < s1;
            int pk = on ? nodeIdx[i + j] : 0;
            a[j] = on ? att[i + j] : 0.f;
            row[j] = pk >> 6;
            pos[j] = pk & 63;
        }
        #pragma unroll
        for (int j = 0; j < 8; ++j) {
            acc0 += a[j] * __bfloat162float(tEU[(size_t)row[j] * RP + l]);
            if (l < 14) acc1 += a[j] * __bfloat162float(tEU[(size_t)row[j] * RP + 64 + l]);
            else        acc1 += a[j] * tpos[pos[j] * MSL + (l - 14)];
        }
    }

    float inv = 1.f / fmaxf(segcnt[b], 1.f);
    out[(size_t)b * D + l] = acc0 * inv;
    out[(size_t)b * D + 64 + l] = acc1 * inv;
}

extern "C" void kernel_launch(void* const* d_in, const int* in_sizes, int n_in,
                              void* d_out, int out_size, void* d_ws, size_t ws_size,
                              hipStream_t stream) {
    const float* query_feat   = (const float*)d_in[0];
    const float* product_feat = (const float*)d_in[1];
    const float* Wq = (const float*)d_in[2];
    const float* bq = (const float*)d_in[3];
    const float* Wp = (const float*)d_in[4];
    const float* bp = (const float*)d_in[5];
    const float* pos_table = (const float*)d_in[6];
    const float* Wn = (const float*)d_in[7];
    const float* bn = (const float*)d_in[8];
    const float* Wc = (const float*)d_in[9];
    const float* Wa = (const float*)d_in[10];
    const int* qpos   = (const int*)d_in[11];
    const int* ppos   = (const int*)d_in[12];
    const int* qbatch = (const int*)d_in[13];
    const int* pbatch = (const int*)d_in[14];
    const int* cnt    = (const int*)d_in[15];

    int NQ = in_sizes[11];
    int T  = in_sizes[12];   // total product nodes
    int P  = in_sizes[15];
    int B  = out_size / D;
    int NR = NQ + P;         // rows in unified tables
    int NN = NQ + T;         // total node-list entries
    float* out = (float*)d_out;

    // workspace layout (256B aligned chunks)
    char* w = (char*)d_ws;
    size_t off = 0;
    auto take = [&](size_t bytes) -> char* {
        char* p = w + off;
        off = (off + bytes + 255) & ~(size_t)255;
        return p;
    };
    int*   nodeCnt = (int*)  take((size_t)B * 4);
    size_t zeroBytes = off;
    float* segsum   = (float*)take((size_t)B * D * 4);
    float* segcnt   = (float*)take((size_t)B * 4);
    float* tpos  = (float*)take(MSL * MSL * 4);
    __hip_bfloat16* posWnbf = (__hip_bfloat16*)take(MSL * D * 2);
    __hip_bfloat16* cWcbf   = (__hip_bfloat16*)take((size_t)B * D * 2);
    __hip_bfloat16* Wqbf = (__hip_bfloat16*)take(80 * 128 * 2);
    __hip_bfloat16* Wpbf = (__hip_bfloat16*)take(80 * 128 * 2);
    __hip_bfloat16* Wnbf = (__hip_bfloat16*)take(128 * 128 * 2);
    __hip_bfloat16* Wabf = (__hip_bfloat16*)take(128 * 2);
    int nC = (P + 255) / 256;
    int* chunkSum = (int*)take((size_t)nC * 4);
    int* chunkOff = (int*)take((size_t)nC * 4);
    int* prodOff  = (int*)take((size_t)P * 4);
    int* segOffA  = (int*)take((size_t)(B + 1) * 4);
    int* cursor   = (int*)take((size_t)B * 4);
    int* nodeIdx  = (int*)take((size_t)NN * 4);
    int* nodeSeg  = (int*)take((size_t)NN * 4);
    float* att    = (float*)take((size_t)NN * 4);
    __hip_bfloat16* tEU  = (__hip_bfloat16*)take((size_t)NR * RP * 2);
    __hip_bfloat16* eWnU = (__hip_bfloat16*)take((size_t)NR * D * 2);
    (void)ws_size; (void)n_in;

    hipMemsetAsync(nodeCnt, 0, zeroBytes, stream);

    hipLaunchKernelGGL(k_tables2, dim3(8), dim3(256), 0, stream, pos_table, Wn, tpos, posWnbf);
    hipLaunchKernelGGL(k_convW, dim3((80 * 128 + 128 * 128 + 128 + 255) / 256), dim3(256), 0,
                       stream, Wq, Wp, Wn, Wa, Wqbf, Wpbf, Wnbf, Wabf);
    hipLaunchKernelGGL(k_scanA, dim3(nC), dim3(256), 0, stream, cnt, P, chunkSum);
    hipLaunchKernelGGL(k_scanB, dim3(1), dim3(1024), 0, stream, chunkSum, nC, chunkOff);
    hipLaunchKernelGGL(k_scanC, dim3(nC), dim3(256), 0, stream, cnt, P, chunkOff, prodOff);

    hipLaunchKernelGGL(k_cnt2, dim3((NR + 255) / 256), dim3(256), 0, stream,
                       qbatch, pbatch, cnt, NQ, P, nodeCnt);
    hipLaunchKernelGGL(k_scanSeg, dim3(1), dim3(1024), 0, stream, nodeCnt, B, segOffA, cursor);
    hipLaunchKernelGGL(k_rank2, dim3((NR + 255) / 256), dim3(256), 0, stream,
                       qbatch, pbatch, qpos, ppos, cnt, prodOff, NQ, P, cursor,
                       nodeIdx, nodeSeg);

    int nTilesQ = (NQ + 63) / 64, nTilesP = (P + 63) / 64;
    hipLaunchKernelGGL(k_branch3, dim3(768), dim3(256), 0, stream,
                       query_feat, product_feat, Wqbf, Wpbf, bq, bp, Wnbf,
                       NQ, P, nTilesQ, nTilesQ + nTilesP, tEU, eWnU);

    hipLaunchKernelGGL(k_segsum3, dim3(B), dim3(128), 0, stream,
                       tEU, nodeIdx, segOffA, tpos, B, segsum, segcnt);
    hipLaunchKernelGGL(k_coarse, dim3((B + 15) / 16), dim3(256), 0, stream,
                       segsum, segcnt, Wc, bn, B, cWcbf);

    hipLaunchKernelGGL(k_attw, dim3((NN + 63) / 64), dim3(256), 0, stream,
                       eWnU, cWcbf, posWnbf, Wabf, nodeIdx, nodeSeg, NN, att);
    hipLaunchKernelGGL(k_pool, dim3((B + 3) / 4), dim3(256), 0, stream,
                       tEU, att, tpos, nodeIdx, segOffA, segcnt, B, out);
}